// Round 1
// baseline (631.404 us; speedup 1.0000x reference)
//
#include <hip/hip_runtime.h>
#include <stdint.h>

// SNN forward with STP/STDP, delays {1,2,3,5}, B=8 T=64 NI=256 N=512 NO=32 D=4.
// Strategy: persistent kernel, 256 blocks = 8 batches x 32 o-chunks(16 o's).
// Each lane owns 32 synapses (e = e_grp + 16*i, fixed o): w_stdp + Wval + A_p +
// A_d + delay_idx live in REGISTERS for all 64 steps. Cross-block recurrent data
// (spike/w_p/x_bar records) goes through global rec buffers with per-(b,t)
// release/acquire counters (flag sync, no grid barrier, no cooperative launch).

#define B  8
#define T  64
#define NI 256
#define NN 512
#define NO 32
#define DD 4

#define NBLK 256
#define TPB  256
#define OPB  16          // o's per block
#define SPL  32          // synapses per lane

#define REC_ELEMS (T*B*NN)   // 262144 floats per record array

__global__ __launch_bounds__(TPB, 1)
void snn_main(const float* __restrict__ inputs,
              const float* __restrict__ w,
              const float* __restrict__ w_in,
              const float* __restrict__ dmap,
              const int*   __restrict__ delays,
              const float* __restrict__ w_signs,
              const float* __restrict__ p,
              const float* __restrict__ A_p,
              const float* __restrict__ A_d,
              float* __restrict__ rec_out,
              float* __restrict__ rec_wp,
              float* __restrict__ rec_xb,
              unsigned int* __restrict__ cnt)
{
    // LDS: sxq[e][d] = {syn_p, xbar with sign bit = delayed spike X}. 16 KB.
    // Aliased as w_in staging buffer during the prologue (fully rewritten each step).
    __shared__ float2 sxq[NN*DD];
    __shared__ float  inp_s[T*OPB];   // 4 KB  per-block input-current slice
    __shared__ float  red[64];        // wave partials for the e-reduction

    const int tid     = threadIdx.x;
    const int bid     = blockIdx.x;
    const int b       = bid & 7;      // bid%8 -> same-b blocks land on one XCD (heuristic)
    const int chunk   = bid >> 3;
    const int o_base  = chunk * OPB;
    const int o_local = tid & 15;
    const int e_grp   = tid >> 4;     // 0..15
    const int o       = o_base + o_local;

    // ---------------- prologue: per-lane synapse constants (registers) -------
    float wv[SPL], ap[SPL], ad[SPL], ws[SPL];
    unsigned long long didx = 0ull;
    #pragma unroll
    for (int i = 0; i < SPL; ++i) {
        const int e = e_grp + 16*i;
        wv[i] = w_signs[e] * fabsf(w[e*NN + o]);   // signed magnitude weight
        ap[i] = A_p[e*NN + o];
        ad[i] = A_d[e*NN + o];
        int d = 0;                                  // argmax_d of one-hot dmap
        if (dmap[1*NN*NN + e*NN + o] != 0.0f) d = 1;
        if (dmap[2*NN*NN + e*NN + o] != 0.0f) d = 2;
        if (dmap[3*NN*NN + e*NN + o] != 0.0f) d = 3;
        didx |= (unsigned long long)d << (2*i);
        ws[i] = 1.0f;                               // w_stdp init
    }
    const int del0 = delays[0], del1 = delays[1], del2 = delays[2], del3 = delays[3];

    // ---------------- prologue: inp[b,t,o] slice = inputs @ w_in -------------
    {
        float* win = (float*)sxq;                   // 4096 floats, prologue-only alias
        for (int k = tid; k < NI*OPB; k += TPB) {
            const int c = k >> 4, oo = k & 15;
            win[c*OPB + oo] = w_in[c*NN + o_base + oo];
        }
        __syncthreads();
        #pragma unroll
        for (int j = 0; j < 4; ++j) {
            const int tj = e_grp*4 + j;
            const float* inrow = inputs + (size_t)(b*T + tj)*NI;
            float a = 0.f;
            for (int c = 0; c < NI; ++c) a += inrow[c] * win[c*OPB + o_local];
            inp_s[tj*OPB + o_local] = a;
        }
        __syncthreads();
    }

    // neuron state, replicated across the 16 e_grp threads sharing an o
    float mem = 0.f, w_p = 0.f, x_bar = 0.f, u_pot = 0.f, u_dep = 0.f;
    const float p_o  = p[o];
    const float pd_o = (p_o < 0.f) ? 1.f : 0.f;
    unsigned int* mycnt = cnt + b*T;

    // stage delayed records for one delay slot into LDS
    auto stage = [&](int s, int d) {
        const float* po_ = rec_out + (size_t)(s*B + b)*NN;
        const float* pw_ = rec_wp  + (size_t)(s*B + b)*NN;
        const float* px_ = rec_xb  + (size_t)(s*B + b)*NN;
        #pragma unroll
        for (int k = 0; k < 2; ++k) {
            const int e = k*256 + tid;
            const float out = po_[e], wpv = pw_[e], xbv = px_[e];
            const float sp  = out * (1.f + wpv);
            // x_bar >= 0 always: pack delayed spike X into the sign bit
            const unsigned int xq = __float_as_uint(xbv) | (out != 0.f ? 0x80000000u : 0u);
            sxq[e*DD + d] = make_float2(sp, __uint_as_float(xq));
        }
    };

    for (int t = 0; t < T; ++t) {
        // ---- phase A: local neuron dynamics + publish records ----
        const float spike = (mem - 1.0f > 0.0f) ? 1.0f : 0.0f;
        if (e_grp == 0) {
            const int base = (t*B + b)*NN + o;
            rec_out[base] = spike;
            rec_wp[base]  = w_p;      // pre-update values, as in reference
            rec_xb[base]  = x_bar;
        }
        const float pg  = spike * fmaxf(u_pot, 0.f);  // gates use pre-update u's
        const float udr = fmaxf(u_dep, 0.f);
        w_p   = 0.85f*w_p + spike * p_o * (1.f + pd_o*w_p);
        x_bar = 0.95f*x_bar + 0.05f*spike;
        u_pot = 0.95f*u_pot + 0.05f*mem;              // pre-update mem
        u_dep = 0.95f*u_dep + 0.05f*mem;
        __syncthreads();  // drains record stores (vmcnt) + guards sxq reuse
        if (tid == 0)
            __hip_atomic_fetch_add(mycnt + t, 1u, __ATOMIC_RELEASE, __HIP_MEMORY_SCOPE_AGENT);

        // ---- phase B: stage delays >=2 (already synced), poll, stage delay 1 ----
        stage((t - del1) & 63, 1);
        stage((t - del2) & 63, 2);
        stage((t - del3) & 63, 3);
        if (t >= 1 && tid == 0) {
            int guard = 0;
            while (__hip_atomic_load(mycnt + (t-1), __ATOMIC_RELAXED, __HIP_MEMORY_SCOPE_AGENT) < 32u) {
                __builtin_amdgcn_s_sleep(2);
                if (++guard > (1<<22)) break;   // fail loud (wrong result) not hung
            }
            (void)__hip_atomic_load(mycnt + (t-1), __ATOMIC_ACQUIRE, __HIP_MEMORY_SCOPE_AGENT);
        }
        __syncthreads();
        stage((t - del0) & 63, 0);
        __syncthreads();

        // ---- phase C: 32 synapses/lane: syn accumulation + STDP update ----
        float acc = 0.f;
        #pragma unroll
        for (int i = 0; i < SPL; ++i) {
            const int d = (int)((didx >> (2*i)) & 3ull);
            const float2 v = sxq[(e_grp + 16*i)*DD + d];
            acc += v.x * (wv[i] * ws[i]);                 // syn uses OLD w_stdp
            const unsigned int xqi = __float_as_uint(v.y);
            float dep = ad[i] * udr;
            dep = ((int)xqi < 0) ? dep : 0.f;             // X in sign bit (catches -0.0)
            const float pot = (ap[i] * pg) * fabsf(v.y);
            ws[i] = fminf(fmaxf(ws[i] + pot - dep, 0.f), 2.f);
        }
        // reduce over e: intra-wave xor-shuffles, then 4 wave partials via LDS
        float a2 = acc + __shfl_xor(acc, 16);
        a2 += __shfl_xor(a2, 32);
        if ((tid & 63) < 16) red[(tid >> 6)*16 + o_local] = a2;
        __syncthreads();
        const float syn = red[o_local] + red[16 + o_local] + red[32 + o_local] + red[48 + o_local];
        mem = 0.9f*mem + inp_s[t*OPB + o_local] + syn - spike;
    }
}

// h2[b,t,o] = sum_n rec_out[t,b,n] * w_out[n,o]
__global__ __launch_bounds__(256)
void snn_h2(const float* __restrict__ rec_out,
            const float* __restrict__ w_out,
            float* __restrict__ h2)
{
    const int bt = blockIdx.x;          // b*64 + t
    const int b = bt >> 6, t = bt & 63;
    const int tid = threadIdx.x;
    const int o = tid & 31, g = tid >> 5;
    const float* ro = rec_out + (size_t)(t*B + b)*NN + g*64;
    float a = 0.f;
    #pragma unroll 8
    for (int j = 0; j < 64; ++j) a += ro[j] * w_out[(g*64 + j)*NO + o];
    __shared__ float r2[8][NO];
    r2[g][o] = a;
    __syncthreads();
    if (tid < NO) {
        float s = 0.f;
        #pragma unroll
        for (int gg = 0; gg < 8; ++gg) s += r2[gg][tid];
        h2[bt*NO + tid] = s;
    }
}

// leaky-integrator readout scan over t
__global__ void snn_scan(const float* __restrict__ h2, float* __restrict__ out)
{
    const int tid = threadIdx.x;        // 256 = 8 b * 32 o
    const int b = tid >> 5, o = tid & 31;
    float st = 0.f;
    for (int t = 0; t < T; ++t) {
        st = 0.9f*st + h2[(b*T + t)*NO + o];
        out[(b*T + t)*NO + o] = st;
    }
}

extern "C" void kernel_launch(void* const* d_in, const int* in_sizes, int n_in,
                              void* d_out, int out_size, void* d_ws, size_t ws_size,
                              hipStream_t stream)
{
    const float* inputs  = (const float*)d_in[0];
    const float* w       = (const float*)d_in[1];
    const float* w_in    = (const float*)d_in[2];
    const float* w_out   = (const float*)d_in[3];
    const float* dmap    = (const float*)d_in[4];
    const int*   delays  = (const int*)  d_in[5];
    const float* w_signs = (const float*)d_in[6];
    const float* p       = (const float*)d_in[7];
    const float* A_p     = (const float*)d_in[8];
    const float* A_d     = (const float*)d_in[9];

    char* wsb = (char*)d_ws;
    float* rec_out = (float*)(wsb);
    float* rec_wp  = (float*)(wsb + (size_t)REC_ELEMS*4);
    float* rec_xb  = (float*)(wsb + (size_t)REC_ELEMS*8);
    unsigned int* cnt = (unsigned int*)(wsb + (size_t)REC_ELEMS*12);
    float* h2      = (float*)(wsb + (size_t)REC_ELEMS*12 + 4096);

    // rec buffers + counters must start at zero every launch (ws is poisoned)
    hipMemsetAsync(d_ws, 0, (size_t)REC_ELEMS*12 + 4096, stream);

    hipLaunchKernelGGL(snn_main, dim3(NBLK), dim3(TPB), 0, stream,
                       inputs, w, w_in, dmap, delays, w_signs, p, A_p, A_d,
                       rec_out, rec_wp, rec_xb, cnt);
    hipLaunchKernelGGL(snn_h2, dim3(B*T), dim3(256), 0, stream,
                       rec_out, w_out, h2);
    hipLaunchKernelGGL(snn_scan, dim3(1), dim3(256), 0, stream,
                       h2, (float*)d_out);
}

// Round 2
// 276.116 us; speedup vs baseline: 2.2867x; 2.2867x over previous
//
#include <hip/hip_runtime.h>
#include <stdint.h>

// SNN forward with STP/STDP, delays {1,2,3,5}, B=8 T=64 NI=256 N=512 NO=32 D=4.
// Persistent dataflow kernel: 256 blocks = 8 batches x 32 o-chunks (16 o's).
// Each lane owns 32 synapses (e = e_grp + 16*i, fixed o): w_stdp/Wval/A_p/A_d +
// precomputed LDS addr live in REGISTERS for all 64 steps.
// Cross-block recurrence: ONE packed 8B record per (t,b,n) = {syn_p, xbar|spikebit},
// written once with relaxed AGENT-scope atomic store (write-through, NO fences),
// consumed with relaxed AGENT-scope poll loads against a 0xFFFFFFFF sentinel
// (impossible xbar bit pattern). Data-as-flag => no release/acquire (no per-step
// buffer_wbl2/buffer_inv), no barrier lockstep, unbounded-safe block skew.

#define B  8
#define T  64
#define NI 256
#define NN 512
#define NO 32
#define DD 4

#define NBLK 256
#define TPB  256
#define OPB  16          // o's per block
#define SPL  32          // synapses per lane
#define EPAD 516         // padded per-d LDS plane stride (float2 elems)

#define REC_ELEMS (T*B*NN)   // packed 8B records

__device__ __forceinline__ unsigned long long rec_load(const unsigned long long* p) {
    return __hip_atomic_load(p, __ATOMIC_RELAXED, __HIP_MEMORY_SCOPE_AGENT);
}
__device__ __forceinline__ void rec_store(unsigned long long* p, unsigned long long v) {
    __hip_atomic_store(p, v, __ATOMIC_RELAXED, __HIP_MEMORY_SCOPE_AGENT);
}
__device__ __forceinline__ bool is_sentinel(unsigned long long v) {
    return (unsigned int)(v >> 32) == 0xFFFFFFFFu;   // xq == -NaN: impossible for real data
}

__global__ __launch_bounds__(TPB, 1)
void snn_main(const float* __restrict__ inputs,
              const float* __restrict__ w,
              const float* __restrict__ w_in,
              const float* __restrict__ dmap,
              const int*   __restrict__ delays,
              const float* __restrict__ w_signs,
              const float* __restrict__ p,
              const float* __restrict__ A_p,
              const float* __restrict__ A_d,
              unsigned long long* __restrict__ rec)
{
    // LDS: sxq[d][e] padded planes = {syn_p, xbar|spikebit}. 16512 B.
    // Write (e=tid consecutive, d fixed): bank = (8d+2e)%32 -> 2-way (free).
    // Read (e = e_grp+16i, d per-lane): bank = (8d+2e_grp)%32 -> 16 distinct, conflict-free.
    __shared__ float2 sxq[DD*EPAD];
    __shared__ float  inp_s[T*OPB];   // per-block input-current slice
    __shared__ float  red[64];        // wave partials for the e-reduction

    const int tid     = threadIdx.x;
    const int bid     = blockIdx.x;
    const int b       = bid & 7;
    const int chunk   = bid >> 3;
    const int o_base  = chunk * OPB;
    const int o_local = tid & 15;
    const int e_grp   = tid >> 4;     // 0..15
    const int o       = o_base + o_local;

    // ---- publish slot 0 (all-zero record) FIRST so other blocks' t=1 polls never
    // wait on our prologue ----
    if (tid < OPB) {
        rec_store(rec + (size_t)(0*B + b)*NN + o_base + tid, 0ull);
    }

    // ---------------- per-lane synapse constants (registers) -----------------
    float wv[SPL], ap[SPL], ad[SPL], ws[SPL];
    int   laddr[SPL];                 // precomputed LDS byte offset of (d,e) slot
    #pragma unroll
    for (int i = 0; i < SPL; ++i) {
        const int e = e_grp + 16*i;
        wv[i] = w_signs[e] * fabsf(w[e*NN + o]);
        ap[i] = A_p[e*NN + o];
        ad[i] = A_d[e*NN + o];
        int d = 0;                    // argmax_d of one-hot dmap
        if (dmap[1*NN*NN + e*NN + o] != 0.0f) d = 1;
        if (dmap[2*NN*NN + e*NN + o] != 0.0f) d = 2;
        if (dmap[3*NN*NN + e*NN + o] != 0.0f) d = 3;
        ws[i]    = 1.0f;
        laddr[i] = (d*EPAD + e) * 8;
    }
    int del[DD];
    #pragma unroll
    for (int d = 0; d < DD; ++d) del[d] = delays[d];

    // ---------------- prologue: inp[b,t,o] slice = inputs @ w_in -------------
    {
        float* win = (float*)sxq;     // 4096 floats alias, prologue-only
        for (int k = tid; k < NI*OPB; k += TPB) {
            const int c = k >> 4, oo = k & 15;
            win[c*OPB + oo] = w_in[c*NN + o_base + oo];
        }
        __syncthreads();
        #pragma unroll
        for (int j = 0; j < 4; ++j) {
            const int tj = e_grp*4 + j;
            const float* inrow = inputs + (size_t)(b*T + tj)*NI;
            float a = 0.f;
            for (int c = 0; c < NI; ++c) a += inrow[c] * win[c*OPB + o_local];
            inp_s[tj*OPB + o_local] = a;
        }
        __syncthreads();
    }

    // zero-fill sxq for step 0 (all delays > 0 => all gathered slots are zero)
    #pragma unroll
    for (int d = 0; d < DD; ++d) {
        sxq[d*EPAD + tid]       = make_float2(0.f, 0.f);
        sxq[d*EPAD + 256 + tid] = make_float2(0.f, 0.f);
    }
    __syncthreads();

    // neuron state, replicated across the 16 e_grp threads sharing an o
    float mem = 0.f, w_p = 0.f, x_bar = 0.f, u_pot = 0.f, u_dep = 0.f;
    const float p_o  = p[o];
    const float pd_o = (p_o < 0.f) ? 1.f : 0.f;

    unsigned long long pf[DD][2];     // prefetched records for next step (d with del>1)

    for (int t = 0; t < T; ++t) {
        // ---- issue prefetch (delays >= 2) for step t+1: latency hidden by C ----
        if (t + 1 < T) {
            #pragma unroll
            for (int d = 0; d < DD; ++d) {
                if (del[d] > 1 && t + 1 >= del[d]) {
                    const int s = (t + 1 - del[d]) & 63;
                    const unsigned long long* src = rec + (size_t)(s*B + b)*NN + tid;
                    pf[d][0] = rec_load(src);
                    pf[d][1] = rec_load(src + 256);
                }
            }
        }

        // ---- phase C: 32 synapses/lane: syn accumulation + STDP update ----
        const float spike = (mem > 1.0f) ? 1.0f : 0.0f;
        const float pg  = spike * fmaxf(u_pot, 0.f);   // gates use pre-update u's
        const float udr = fmaxf(u_dep, 0.f);
        float acc = 0.f;
        #pragma unroll
        for (int i = 0; i < SPL; ++i) {
            const float2 v = *(const float2*)((const char*)sxq + laddr[i]);
            acc = fmaf(v.x, wv[i]*ws[i], acc);         // syn uses OLD w_stdp
            const unsigned int xu = __float_as_uint(v.y);
            const float dep = ((int)xu < 0) ? ad[i]*udr : 0.f;  // X in sign bit
            const float pot = (ap[i]*pg) * fabsf(v.y);
            ws[i] = fminf(fmaxf(ws[i] + pot - dep, 0.f), 2.f);
        }
        // reduce over e: intra-wave xor-shuffles, then 4 wave partials via LDS
        float a2 = acc + __shfl_xor(acc, 16);
        a2 += __shfl_xor(a2, 32);
        if ((tid & 63) < 16) red[(tid >> 6)*16 + o_local] = a2;
        __syncthreads();   // B2: all sxq reads + red writes done
        const float syn = red[o_local] + red[16 + o_local] + red[32 + o_local] + red[48 + o_local];

        // ---- state updates (reference order; u's use pre-update mem) ----
        const float wp_new = 0.85f*w_p + spike * p_o * (1.f + pd_o*w_p);
        const float xb_new = 0.95f*x_bar + 0.05f*spike;
        u_pot = 0.95f*u_pot + 0.05f*mem;
        u_dep = 0.95f*u_dep + 0.05f*mem;
        mem   = 0.9f*mem + inp_s[t*OPB + o_local] + syn - spike;
        w_p   = wp_new;
        x_bar = xb_new;

        // ---- publish record for step t+1 ASAP (pre-update values of t+1) ----
        if (t + 1 < T && tid < OPB) {
            const float spike1 = (mem > 1.0f) ? 1.0f : 0.0f;
            const float sp = spike1 * (1.f + w_p);
            const unsigned int xu = __float_as_uint(x_bar) | (spike1 != 0.f ? 0x80000000u : 0u);
            const unsigned long long pk =
                ((unsigned long long)xu << 32) | (unsigned int)__float_as_uint(sp);
            rec_store(rec + (size_t)((t+1)*B + b)*NN + o_base + tid, pk);
        }

        // ---- stage step t+1 into LDS: delay-1 load+poll, others sentinel-check pf ----
        if (t + 1 < T) {
            #pragma unroll
            for (int d = 0; d < DD; ++d) {
                unsigned long long v0 = 0ull, v1 = 0ull;
                if (t + 1 >= del[d]) {
                    const int s = (t + 1 - del[d]) & 63;
                    const unsigned long long* src = rec + (size_t)(s*B + b)*NN + tid;
                    if (del[d] > 1) { v0 = pf[d][0]; v1 = pf[d][1]; }
                    else            { v0 = rec_load(src); v1 = rec_load(src + 256); }
                    int guard = 0;
                    while (is_sentinel(v0)) {
                        __builtin_amdgcn_s_sleep(1);
                        v0 = rec_load(src);
                        if (++guard > (1 << 24)) break;   // fail loud, not hung
                    }
                    guard = 0;
                    while (is_sentinel(v1)) {
                        __builtin_amdgcn_s_sleep(1);
                        v1 = rec_load(src + 256);
                        if (++guard > (1 << 24)) break;
                    }
                }
                sxq[d*EPAD + tid] =
                    make_float2(__uint_as_float((unsigned int)v0),
                                __uint_as_float((unsigned int)(v0 >> 32)));
                sxq[d*EPAD + 256 + tid] =
                    make_float2(__uint_as_float((unsigned int)v1),
                                make_float2(0.f,0.f).x + __uint_as_float((unsigned int)(v1 >> 32)));
            }
        }
        __syncthreads();   // B-end: sxq staged for t+1; red reads of t done block-wide
    }
}

// h2[b,t,o] = sum_n spike[t,b,n] * w_out[n,o]; spike = sign bit of packed record
__global__ __launch_bounds__(256)
void snn_h2(const unsigned long long* __restrict__ rec,
            const float* __restrict__ w_out,
            float* __restrict__ h2)
{
    const int bt = blockIdx.x;          // b*64 + t
    const int b = bt >> 6, t = bt & 63;
    const int tid = threadIdx.x;
    const int o = tid & 31, g = tid >> 5;
    const unsigned long long* ro = rec + (size_t)(t*B + b)*NN + g*64;
    float a = 0.f;
    #pragma unroll 8
    for (int j = 0; j < 64; ++j)
        if ((long long)ro[j] < 0) a += w_out[(g*64 + j)*NO + o];
    __shared__ float r2[8][NO];
    r2[g][o] = a;
    __syncthreads();
    if (tid < NO) {
        float s = 0.f;
        #pragma unroll
        for (int gg = 0; gg < 8; ++gg) s += r2[gg][tid];
        h2[bt*NO + tid] = s;
    }
}

// leaky-integrator readout scan over t
__global__ void snn_scan(const float* __restrict__ h2, float* __restrict__ out)
{
    const int tid = threadIdx.x;        // 256 = 8 b * 32 o
    const int b = tid >> 5, o = tid & 31;
    float st = 0.f;
    for (int t = 0; t < T; ++t) {
        st = 0.9f*st + h2[(b*T + t)*NO + o];
        out[(b*T + t)*NO + o] = st;
    }
}

extern "C" void kernel_launch(void* const* d_in, const int* in_sizes, int n_in,
                              void* d_out, int out_size, void* d_ws, size_t ws_size,
                              hipStream_t stream)
{
    const float* inputs  = (const float*)d_in[0];
    const float* w       = (const float*)d_in[1];
    const float* w_in    = (const float*)d_in[2];
    const float* w_out   = (const float*)d_in[3];
    const float* dmap    = (const float*)d_in[4];
    const int*   delays  = (const int*)  d_in[5];
    const float* w_signs = (const float*)d_in[6];
    const float* p       = (const float*)d_in[7];
    const float* A_p     = (const float*)d_in[8];
    const float* A_d     = (const float*)d_in[9];

    char* wsb = (char*)d_ws;
    unsigned long long* rec = (unsigned long long*)wsb;            // 2 MB packed records
    float* h2 = (float*)(wsb + (size_t)REC_ELEMS*8);               // 64 KB

    // sentinel-fill records (0xFF bytes -> hi word 0xFFFFFFFF = "unwritten")
    hipMemsetAsync(rec, 0xFF, (size_t)REC_ELEMS*8, stream);

    hipLaunchKernelGGL(snn_main, dim3(NBLK), dim3(TPB), 0, stream,
                       inputs, w, w_in, dmap, delays, w_signs, p, A_p, A_d, rec);
    hipLaunchKernelGGL(snn_h2, dim3(B*T), dim3(256), 0, stream,
                       rec, w_out, h2);
    hipLaunchKernelGGL(snn_scan, dim3(1), dim3(256), 0, stream,
                       h2, (float*)d_out);
}